// Round 8
// baseline (433.334 us; speedup 1.0000x reference)
//
#include <hip/hip_runtime.h>
#include <math.h>

#define BATCH 4
#define TSEQ  2048
#define CEMB  1024
#define NHEAD 16
#define HD    64
#define MROWS (BATCH * TSEQ)   // 8192
#define QSCALE 11.5415603271f  // 8 * log2(e): softmax runs in exp2 domain

typedef _Float16 half8 __attribute__((ext_vector_type(8)));
typedef _Float16 half4 __attribute__((ext_vector_type(4)));
typedef _Float16 half2 __attribute__((ext_vector_type(2)));
typedef float    floatx4 __attribute__((ext_vector_type(4)));

#define GLOBAL_AS __attribute__((address_space(1)))
#define LDS_AS    __attribute__((address_space(3)))

__device__ __forceinline__ void lds_dma16(const _Float16* g, _Float16* l) {
    __builtin_amdgcn_global_load_lds((const GLOBAL_AS unsigned int*)g,
                                     (LDS_AS unsigned int*)l, 16, 0, 0);
}

// raw v_exp_f32 (2^x). VALU interlocks handle the hazard; exp2(-inf)=0.
__device__ __forceinline__ float fast_exp2(float x) {
    float r; asm("v_exp_f32 %0, %1" : "=v"(r) : "v"(x)); return r;
}

// packed f32->f16 conversion: 2 v_cvt_pkrtz instead of ~6 cvt+pack ops.
__device__ __forceinline__ half4 pack4(float a0, float a1, float a2, float a3) {
    half2 lo = __builtin_bit_cast(half2, __builtin_amdgcn_cvt_pkrtz(a0, a1));
    half2 hi = __builtin_bit_cast(half2, __builtin_amdgcn_cvt_pkrtz(a2, a3));
    return (half4){lo[0], lo[1], hi[0], hi[1]};
}

// ---------------------------------------------------------------------------
// Kernel 0: fp32 -> fp16 convert prepass (float4 -> half4)
// ---------------------------------------------------------------------------
__global__ __launch_bounds__(256)
void cvt_fp16(const float* __restrict__ x, const float* __restrict__ wa,
              const float* __restrict__ wp, _Float16* __restrict__ x16,
              _Float16* __restrict__ wa16, _Float16* __restrict__ wp16)
{
    const int n1 = (BATCH * TSEQ * CEMB) / 4;
    const int n2 = (3 * CEMB * CEMB) / 4;
    int i = blockIdx.x * 256 + threadIdx.x;
    const float* src; _Float16* dst; int j;
    if (i < n1)            { src = x;  dst = x16;  j = i; }
    else if (i < n1 + n2)  { src = wa; dst = wa16; j = i - n1; }
    else                   { src = wp; dst = wp16; j = i - n1 - n2; }
    float4 v = ((const float4*)src)[j];
    half4 h = { (_Float16)v.x, (_Float16)v.y, (_Float16)v.z, (_Float16)v.w };
    ((half4*)dst)[j] = h;
}

// ---------------------------------------------------------------------------
// GEMM staging: 128x32 fp16 tile, DMA, XOR swizzle c = pc ^ (row&3).
// ---------------------------------------------------------------------------
__device__ __forceinline__ void stage32(const _Float16* __restrict__ gbase,
                                        _Float16* __restrict__ lds,
                                        int row0, int kk, int tid)
{
#pragma unroll
    for (int p = 0; p < 2; ++p) {
        int ci  = p * 256 + tid;
        int row = ci >> 2, pcc = ci & 3;
        int c   = pcc ^ (row & 3);
        lds_dma16(gbase + (size_t)(row0 + row) * CEMB + kk + c * 8, lds + ci * 8);
    }
}

// ---------------------------------------------------------------------------
// Kernel 1: qkv = x16 @ Wa16^T. Epilogue stages C through LDS for coalesced
// half8 stores; v blocks transpose in LDS. q is pre-scaled by 8*log2e.
// XCD swizzle (T1): each XCD owns 8 fixed A row-panels (2MB, L2-resident,
// read 24x each); 8 consecutive blocks per XCD share one B panel (256KB).
// ---------------------------------------------------------------------------
__global__ __launch_bounds__(256)
void qkv_gemm(const _Float16* __restrict__ A, const _Float16* __restrict__ B,
              _Float16* __restrict__ q16, _Float16* __restrict__ k16,
              _Float16* __restrict__ v16)
{
    __shared__ __align__(16) _Float16 smem[16384];   // 32 KB: dbuf tiles / C-tile
    const int tid = threadIdx.x, lane = tid & 63, wave = tid >> 6;
    const int wm = wave & 1, wn = wave >> 1;
    // remap: L = x + 24y in [0,1536); xcd = L%8; m-panel = (L&7) + 8*((L>>3)&7),
    // n-panel = L>>6... bijective (see text). Validated XCD model.
    const int L  = blockIdx.x + 24 * blockIdx.y;
    const int jj = L >> 3;
    const int m0 = ((L & 7) + 8 * (jj & 7)) * 128;
    const int n0 = (jj >> 3) * 128;
    const int l15 = lane & 15, quad = lane >> 4;

    floatx4 acc[4][4];
#pragma unroll
    for (int i = 0; i < 4; ++i)
#pragma unroll
        for (int j = 0; j < 4; ++j) acc[i][j] = (floatx4){0.f, 0.f, 0.f, 0.f};

    stage32(A, smem, m0, 0, tid);
    stage32(B, smem + 8192, n0, 0, tid);
    for (int kt = 0; kt < 32; ++kt) {
        const int cur = kt & 1;
        _Float16* Asc = smem + cur * 4096;
        _Float16* Bsc = smem + 8192 + cur * 4096;
        __syncthreads();                      // drains DMA(kt)
        if (kt < 31) {
            stage32(A, smem + (cur ^ 1) * 4096, m0, (kt + 1) * 32, tid);
            stage32(B, smem + 8192 + (cur ^ 1) * 4096, n0, (kt + 1) * 32, tid);
        }
        half8 af[4], bf[4];
#pragma unroll
        for (int mt = 0; mt < 4; ++mt) {
            int row = wm * 64 + mt * 16 + l15;
            af[mt] = *(const half8*)(Asc + row * 32 + (quad ^ (row & 3)) * 8);
        }
#pragma unroll
        for (int nt = 0; nt < 4; ++nt) {
            int row = wn * 64 + nt * 16 + l15;
            bf[nt] = *(const half8*)(Bsc + row * 32 + (quad ^ (row & 3)) * 8);
        }
#pragma unroll
        for (int mt = 0; mt < 4; ++mt)
#pragma unroll
            for (int nt = 0; nt < 4; ++nt)
                acc[mt][nt] = __builtin_amdgcn_mfma_f32_16x16x32_f16(af[mt], bf[nt], acc[mt][nt], 0, 0, 0);
    }

    __syncthreads();                          // all frag reads done; reuse smem
    const int rbase = quad << 2;
    if (n0 < 2 * CEMB) {
        // --- q/k: C[t][n'] with chunk swizzle pc = (n>>3) ^ (t&15) ---
        const float scale = (n0 < CEMB) ? QSCALE : 1.0f;
#pragma unroll
        for (int mt = 0; mt < 4; ++mt)
#pragma unroll
            for (int nt = 0; nt < 4; ++nt)
#pragma unroll
                for (int r = 0; r < 4; ++r) {
                    int t = wm * 64 + mt * 16 + rbase + r;
                    int n = wn * 64 + nt * 16 + l15;
                    int pc = (n >> 3) ^ (t & 15);
                    smem[t * 128 + pc * 8 + (n & 7)] = (_Float16)(acc[mt][nt][r] * scale);
                }
        __syncthreads();
        const int chunk = tid & 7;
#pragma unroll
        for (int i = 0; i < 8; ++i) {
            int gr = (tid >> 3) + i * 32;     // 0..255: (seg,t)
            int seg = gr >> 7, t = gr & 127;
            int pc = (seg * 8 + chunk) ^ (t & 15);
            half8 v = *(const half8*)(smem + t * 128 + pc * 8);
            int gm = m0 + t, b = gm >> 11, tt = gm & (TSEQ - 1);
            int gnb = n0 + seg * 64;
            _Float16* dst;
            if (n0 < CEMB) {
                int h = gnb >> 6;
                dst = q16 + (((size_t)(b * NHEAD + h)) * TSEQ + tt) * HD;
            } else {
                int h = (gnb - CEMB) >> 6;
                dst = k16 + (((size_t)(b * NHEAD + h)) * TSEQ + tt) * HD;
            }
            *(half8*)(dst + chunk * 8) = v;
        }
    } else {
        // --- v: transpose in LDS: C[n'][t] with pc = (t>>3) ^ (n&15) ---
#pragma unroll
        for (int mt = 0; mt < 4; ++mt)
#pragma unroll
            for (int nt = 0; nt < 4; ++nt)
#pragma unroll
                for (int r = 0; r < 4; ++r) {
                    int t = wm * 64 + mt * 16 + rbase + r;
                    int n = wn * 64 + nt * 16 + l15;
                    int pc = (t >> 3) ^ (n & 15);
                    smem[n * 128 + pc * 8 + (t & 7)] = (_Float16)acc[mt][nt][r];
                }
        __syncthreads();
        const int chunk = tid & 15;           // 16 chunks of 8 along t
        const int b = m0 >> 11, tblk = m0 & (TSEQ - 1);
#pragma unroll
        for (int i = 0; i < 8; ++i) {
            int row = (tid >> 4) + i * 16;    // n' 0..127
            int pc = chunk ^ (row & 15);
            half8 v = *(const half8*)(smem + row * 128 + pc * 8);
            int c2 = n0 - 2 * CEMB + row;
            int h = c2 >> 6, d = c2 & 63;
            *(half8*)(v16 + (((size_t)(b * NHEAD + h)) * HD + d) * TSEQ + tblk + chunk * 8) = v;
        }
    }
}

// ---------------------------------------------------------------------------
// Kernel 2: flash attention. S^T = K·Q^T; P in registers (B-layout) for
// mfma_16x16x16f16 (O^T = V^T·P^T). Cooperative: 4 waves share each tile;
// phase 1 = tiles A+B with shared K frags (2x ILP), phase 2 B-only.
//
// V is NOT staged in LDS: after the XCD remap each bh's K/V is L2-resident
// (FETCH 25MB proved it); V fragments are half4 global loads issued BEFORE
// the softmax VALU block (~200cyc L2 latency hides under it, T14). L1
// catches cross-wave tile reuse (8KB tile vs 32KB L1). Removes half the
// DMA, 16KB LDS, and the V ds_reads (dominant bank-conflict source).
// ---------------------------------------------------------------------------
__device__ __forceinline__ void attn_tile(
    const half8& qf0, const half8& qf1,
    float& m_i, float& l_i, floatx4 (&o)[4],
    const _Float16* __restrict__ Ks, const _Float16* __restrict__ vg,
    bool domask, int l15, int quad, int relq)
{
    floatx4 s[4];
#pragma unroll
    for (int nt = 0; nt < 4; ++nt) {
        int row = nt * 16 + l15;
        int pc0 = quad ^ (row & 7);
        half8 kf0 = *(const half8*)(Ks + row * 64 + pc0 * 8);
        half8 kf1 = *(const half8*)(Ks + row * 64 + (pc0 ^ 4) * 8);
        floatx4 z = (floatx4){0.f, 0.f, 0.f, 0.f};
        z = __builtin_amdgcn_mfma_f32_16x16x32_f16(kf0, qf0, z, 0, 0, 0);
        z = __builtin_amdgcn_mfma_f32_16x16x32_f16(kf1, qf1, z, 0, 0, 0);
        s[nt] = z;
    }
    // V fragment prefetch from L2 — issued before softmax to hide latency
    half4 vf[4][4];
#pragma unroll
    for (int mt = 0; mt < 4; ++mt) {
        const _Float16* vrow = vg + (size_t)(mt * 16 + l15) * TSEQ + quad * 4;
#pragma unroll
        for (int nt = 0; nt < 4; ++nt)
            vf[mt][nt] = *(const half4*)(vrow + nt * 16);
    }
    if (domask) {
#pragma unroll
        for (int nt = 0; nt < 4; ++nt)
#pragma unroll
            for (int r = 0; r < 4; ++r)
                if (nt * 16 + quad * 4 + r > relq) s[nt][r] = -INFINITY;
    }
    float pmax = -INFINITY;
#pragma unroll
    for (int nt = 0; nt < 4; ++nt)
        pmax = fmaxf(pmax, fmaxf(fmaxf(s[nt][0], s[nt][1]), fmaxf(s[nt][2], s[nt][3])));
    if (!__all(pmax <= m_i)) {
        float mx = fmaxf(m_i, pmax);
        mx = fmaxf(mx, __shfl_xor(mx, 16, 64));
        mx = fmaxf(mx, __shfl_xor(mx, 32, 64));
        float alpha = fast_exp2(m_i - mx);
        m_i = mx;
        l_i *= alpha;
#pragma unroll
        for (int mt = 0; mt < 4; ++mt)
#pragma unroll
            for (int r = 0; r < 4; ++r) o[mt][r] *= alpha;
    }
    float rs = 0.f;
    half4 p[4];
#pragma unroll
    for (int nt = 0; nt < 4; ++nt) {
        float p0 = fast_exp2(s[nt][0] - m_i), p1 = fast_exp2(s[nt][1] - m_i);
        float p2 = fast_exp2(s[nt][2] - m_i), p3 = fast_exp2(s[nt][3] - m_i);
        rs += (p0 + p1) + (p2 + p3);
        p[nt] = pack4(p0, p1, p2, p3);
    }
    l_i += rs;   // per-lane partial; reduced once in epilogue
#pragma unroll
    for (int mt = 0; mt < 4; ++mt)
#pragma unroll
        for (int nt = 0; nt < 4; ++nt)
            o[mt] = __builtin_amdgcn_mfma_f32_16x16x16f16(vf[mt][nt], p[nt], o[mt], 0, 0, 0);
}

// dual-tile body: A and B interleaved, shared K/V fragments. B never masked
// here (kt <= qtA < qtB); A masked iff kt == qtA.
__device__ __forceinline__ void attn_tile2(
    const half8& qA0, const half8& qA1, const half8& qB0, const half8& qB1,
    float& mAi, float& lAi, floatx4 (&oA)[4],
    float& mBi, float& lBi, floatx4 (&oB)[4],
    const _Float16* __restrict__ Ks, const _Float16* __restrict__ vg,
    bool maskA, int l15, int quad, int relq)
{
    floatx4 sA[4], sB[4];
#pragma unroll
    for (int nt = 0; nt < 4; ++nt) {
        int row = nt * 16 + l15;
        int pc0 = quad ^ (row & 7);
        half8 kf0 = *(const half8*)(Ks + row * 64 + pc0 * 8);
        half8 kf1 = *(const half8*)(Ks + row * 64 + (pc0 ^ 4) * 8);
        floatx4 zA = (floatx4){0.f, 0.f, 0.f, 0.f};
        floatx4 zB = (floatx4){0.f, 0.f, 0.f, 0.f};
        zA = __builtin_amdgcn_mfma_f32_16x16x32_f16(kf0, qA0, zA, 0, 0, 0);
        zB = __builtin_amdgcn_mfma_f32_16x16x32_f16(kf0, qB0, zB, 0, 0, 0);
        zA = __builtin_amdgcn_mfma_f32_16x16x32_f16(kf1, qA1, zA, 0, 0, 0);
        zB = __builtin_amdgcn_mfma_f32_16x16x32_f16(kf1, qB1, zB, 0, 0, 0);
        sA[nt] = zA; sB[nt] = zB;
    }
    // shared V fragment prefetch (one set feeds both tiles' PV)
    half4 vf[4][4];
#pragma unroll
    for (int mt = 0; mt < 4; ++mt) {
        const _Float16* vrow = vg + (size_t)(mt * 16 + l15) * TSEQ + quad * 4;
#pragma unroll
        for (int nt = 0; nt < 4; ++nt)
            vf[mt][nt] = *(const half4*)(vrow + nt * 16);
    }
    if (maskA) {
#pragma unroll
        for (int nt = 0; nt < 4; ++nt)
#pragma unroll
            for (int r = 0; r < 4; ++r)
                if (nt * 16 + quad * 4 + r > relq) sA[nt][r] = -INFINITY;
    }
    float pA = -INFINITY, pB = -INFINITY;
#pragma unroll
    for (int nt = 0; nt < 4; ++nt) {
        pA = fmaxf(pA, fmaxf(fmaxf(sA[nt][0], sA[nt][1]), fmaxf(sA[nt][2], sA[nt][3])));
        pB = fmaxf(pB, fmaxf(fmaxf(sB[nt][0], sB[nt][1]), fmaxf(sB[nt][2], sB[nt][3])));
    }
    if (!__all((pA <= mAi) && (pB <= mBi))) {
        float mxA = fmaxf(mAi, pA), mxB = fmaxf(mBi, pB);
        mxA = fmaxf(mxA, __shfl_xor(mxA, 16, 64));
        mxB = fmaxf(mxB, __shfl_xor(mxB, 16, 64));
        mxA = fmaxf(mxA, __shfl_xor(mxA, 32, 64));
        mxB = fmaxf(mxB, __shfl_xor(mxB, 32, 64));
        float alA = fast_exp2(mAi - mxA);
        float alB = fast_exp2(mBi - mxB);
        mAi = mxA; mBi = mxB;
        lAi *= alA; lBi *= alB;
#pragma unroll
        for (int mt = 0; mt < 4; ++mt)
#pragma unroll
            for (int r = 0; r < 4; ++r) { oA[mt][r] *= alA; oB[mt][r] *= alB; }
    }
    float rsA = 0.f, rsB = 0.f;
    half4 pAh[4], pBh[4];
#pragma unroll
    for (int nt = 0; nt < 4; ++nt) {
        float a0 = fast_exp2(sA[nt][0] - mAi), b0 = fast_exp2(sB[nt][0] - mBi);
        float a1 = fast_exp2(sA[nt][1] - mAi), b1 = fast_exp2(sB[nt][1] - mBi);
        float a2 = fast_exp2(sA[nt][2] - mAi), b2 = fast_exp2(sB[nt][2] - mBi);
        float a3 = fast_exp2(sA[nt][3] - mAi), b3 = fast_exp2(sB[nt][3] - mBi);
        rsA += (a0 + a1) + (a2 + a3);
        rsB += (b0 + b1) + (b2 + b3);
        pAh[nt] = pack4(a0, a1, a2, a3);
        pBh[nt] = pack4(b0, b1, b2, b3);
    }
    lAi += rsA; lBi += rsB;   // per-lane partials
#pragma unroll
    for (int mt = 0; mt < 4; ++mt)
#pragma unroll
        for (int nt = 0; nt < 4; ++nt) {
            oA[mt] = __builtin_amdgcn_mfma_f32_16x16x16f16(vf[mt][nt], pAh[nt], oA[mt], 0, 0, 0);
            oB[mt] = __builtin_amdgcn_mfma_f32_16x16x16f16(vf[mt][nt], pBh[nt], oB[mt], 0, 0, 0);
        }
}

__global__ __launch_bounds__(256)
void attn_fwd(const _Float16* __restrict__ q16, const _Float16* __restrict__ k16,
              const _Float16* __restrict__ v16, _Float16* __restrict__ o16)
{
    __shared__ __align__(16) _Float16 Ks[2][64 * 64];
    const int tid = threadIdx.x, lane = tid & 63, wave = tid >> 6;
    const int l15 = lane & 15, quad = lane >> 4;

    // R2 remap (measured best): each XCD owns 8 bh -> K/V L2-resident.
    const int L   = blockIdx.x + 16 * blockIdx.y;
    const int qtA = (L >> 3) & 15;             // 0..15
    const int bh  = (L & 7) + ((L >> 7) << 3); // 0..63
    const int qtB = 31 - qtA;                  // 16..31
    const int b = bh >> 4, h = bh & 15;
    const int q0A = qtA * 64, q0B = qtB * 64;
    const _Float16* qp = q16 + (size_t)bh * TSEQ * HD;
    const _Float16* kp = k16 + (size_t)bh * TSEQ * HD;
    const _Float16* vp = v16 + (size_t)bh * HD * TSEQ;

    const int relq = wave * 16 + l15;
    half8 qA0 = *(const half8*)(qp + (size_t)(q0A + relq) * HD + quad * 8);
    half8 qA1 = *(const half8*)(qp + (size_t)(q0A + relq) * HD + 32 + quad * 8);
    half8 qB0 = *(const half8*)(qp + (size_t)(q0B + relq) * HD + quad * 8);
    half8 qB1 = *(const half8*)(qp + (size_t)(q0B + relq) * HD + 32 + quad * 8);

    float mA = -INFINITY, lA = 0.f, mB = -INFINITY, lB = 0.f;
    floatx4 oA[4], oB[4];
#pragma unroll
    for (int mt = 0; mt < 4; ++mt) { oA[mt] = (floatx4){0.f,0.f,0.f,0.f}; oB[mt] = (floatx4){0.f,0.f,0.f,0.f}; }

#define STAGE_K(kt0, buf)                                                      \
    {                                                                          \
        _Float16* kd = Ks[buf];                                                \
        _Pragma("unroll")                                                      \
        for (int p = 0; p < 2; ++p) {                                          \
            int ci = p * 256 + tid;                                            \
            int row = ci >> 3;                                                 \
            int c2 = (ci & 7) ^ (row & 7);                                     \
            lds_dma16(kp + (size_t)((kt0) + row) * HD + c2 * 8, kd + ci * 8);  \
        }                                                                      \
    }

    STAGE_K(0, 0);
    // phase 1: kt = 0..qtA — both tiles, shared K/V frags, interleaved ILP
    for (int kt = 0; kt <= qtA; ++kt) {
        const int cur = kt & 1;
        __syncthreads();
        STAGE_K((kt + 1) * 64, cur ^ 1);      // kt+1 <= qtA+1 <= qtB: valid
        attn_tile2(qA0, qA1, qB0, qB1, mA, lA, oA, mB, lB, oB,
                   Ks[cur], vp + kt * 64, (kt == qtA), l15, quad, relq);
    }
    // phase 2: kt = qtA+1..qtB — B only
    for (int kt = qtA + 1; kt <= qtB; ++kt) {
        const int cur = kt & 1;
        __syncthreads();
        if (kt < qtB) STAGE_K((kt + 1) * 64, cur ^ 1);
        attn_tile(qB0, qB1, mB, lB, oB, Ks[cur], vp + kt * 64,
                  (kt == qtB), l15, quad, relq);
    }
#undef STAGE_K

    // reduce per-lane l partials across the 4 lanes sharing each q-row
    lA += __shfl_xor(lA, 16, 64); lA += __shfl_xor(lA, 32, 64);
    lB += __shfl_xor(lB, 16, 64); lB += __shfl_xor(lB, 32, 64);
    const float invA = 1.f / lA, invB = 1.f / lB;
    const size_t baseA = ((size_t)(b * TSEQ + q0A + relq)) * CEMB + h * HD + quad * 4;
    const size_t baseB = ((size_t)(b * TSEQ + q0B + relq)) * CEMB + h * HD + quad * 4;
#pragma unroll
    for (int mt = 0; mt < 4; ++mt) {
        half4 ha = { (_Float16)(oA[mt][0] * invA), (_Float16)(oA[mt][1] * invA),
                     (_Float16)(oA[mt][2] * invA), (_Float16)(oA[mt][3] * invA) };
        half4 hb = { (_Float16)(oB[mt][0] * invB), (_Float16)(oB[mt][1] * invB),
                     (_Float16)(oB[mt][2] * invB), (_Float16)(oB[mt][3] * invB) };
        *(half4*)(o16 + baseA + mt * 16) = ha;
        *(half4*)(o16 + baseB + mt * 16) = hb;
    }
}

// ---------------------------------------------------------------------------
// Kernel 3: y = attn16 @ Wp16^T + b_proj, fp32 out. 128x128 tile, 512
// blocks. XCD swizzle: each XCD owns 8 A row-panels (2MB) + full Wp (2MB)
// = L2-sized. GRID MUST BE (8, 64) — L in [0,512).
// ---------------------------------------------------------------------------
__global__ __launch_bounds__(256)
void proj_gemm(const _Float16* __restrict__ A, const _Float16* __restrict__ B,
               const float* __restrict__ bias, float* __restrict__ out)
{
    __shared__ __align__(16) _Float16 smem[16384];   // 32 KB dbuf tiles
    const int tid = threadIdx.x, lane = tid & 63, wave = tid >> 6;
    const int wm = wave & 1, wn = wave >> 1;
    const int L  = blockIdx.x + 8 * blockIdx.y;      // 0..511
    const int jj = L >> 3;                            // 0..63
    const int m0 = ((L & 7) + 8 * (jj & 7)) * 128;   // XCD's 8 panels
    const int n0 = (jj >> 3) * 128;                  // 0..7 panels
    const int l15 = lane & 15, quad = lane >> 4;

    floatx4 acc[4][4];
#pragma unroll
    for (int i = 0; i < 4; ++i)
#pragma unroll
        for (int j = 0; j < 4; ++j) acc[i][j] = (floatx4){0.f, 0.f, 0.f, 0.f};

    stage32(A, smem, m0, 0, tid);
    stage32(B, smem + 8192, n0, 0, tid);
    for (int kt = 0; kt < 32; ++kt) {
        const int cur = kt & 1;
        _Float16* Asc = smem + cur * 4096;
        _Float16* Bsc = smem + 8192 + cur * 4096;
        __syncthreads();                      // drains DMA(kt)
        if (kt < 31) {
            stage32(A, smem + (cur ^ 1) * 4096, m0, (kt + 1) * 32, tid);
            stage32(B, smem + 8192 + (cur ^ 1) * 4096, n0, (kt + 1) * 32, tid);
        }
        half8 af[4], bf[4];
#pragma unroll
        for (int mt = 0; mt < 4; ++mt) {
            int row = wm * 64 + mt * 16 + l15;
            af[mt] = *(const half8*)(Asc + row * 32 + (quad ^ (row & 3)) * 8);
        }
#pragma unroll
        for (int nt = 0; nt < 4; ++nt) {
            int row = wn * 64 + nt * 16 + l15;
            bf[nt] = *(const half8*)(Bsc + row * 32 + (quad ^ (row & 3)) * 8);
        }
#pragma unroll
        for (int mt = 0; mt < 4; ++mt)
#pragma unroll
            for (int nt = 0; nt < 4; ++nt)
                acc[mt][nt] = __builtin_amdgcn_mfma_f32_16x16x32_f16(af[mt], bf[nt], acc[mt][nt], 0, 0, 0);
    }

    const int rbase = quad << 2;
#pragma unroll
    for (int mt = 0; mt < 4; ++mt)
#pragma unroll
        for (int nt = 0; nt < 4; ++nt) {
            int gn = n0 + wn * 64 + nt * 16 + l15;
            float bb = bias[gn];
#pragma unroll
            for (int r = 0; r < 4; ++r) {
                int gm = m0 + wm * 64 + mt * 16 + rbase + r;
                out[(size_t)gm * CEMB + gn] = acc[mt][nt][r] + bb;
            }
        }
}

// ---------------------------------------------------------------------------
extern "C" void kernel_launch(void* const* d_in, const int* in_sizes, int n_in,
                              void* d_out, int out_size, void* d_ws, size_t ws_size,
                              hipStream_t stream) {
    const float* x     = (const float*)d_in[0];
    const float* Wattn = (const float*)d_in[1];
    const float* Wproj = (const float*)d_in[2];
    const float* bproj = (const float*)d_in[3];
    float* out = (float*)d_out;

    const size_t nx  = (size_t)BATCH * TSEQ * CEMB;
    const size_t nwa = (size_t)3 * CEMB * CEMB;
    const size_t nwp = (size_t)CEMB * CEMB;
    const size_t per = (size_t)BATCH * NHEAD * TSEQ * HD;

    _Float16* x16    = (_Float16*)d_ws;
    _Float16* wa16   = x16 + nx;
    _Float16* wp16   = wa16 + nwa;
    _Float16* q16    = wp16 + nwp;
    _Float16* k16    = q16 + per;
    _Float16* v16    = k16 + per;
    _Float16* attn16 = x16;   // alias: x16 fully consumed before attn writes

    const int nconv = (int)((nx + nwa + nwp) / 4);
    cvt_fp16<<<nconv / 256, 256, 0, stream>>>(x, Wattn, Wproj, x16, wa16, wp16);
    qkv_gemm<<<dim3(3 * CEMB / 128, MROWS / 128), 256, 0, stream>>>(x16, wa16, q16, k16, v16);
    attn_fwd<<<dim3(16, BATCH * NHEAD), 256, 0, stream>>>(q16, k16, v16, attn16);
    proj_gemm<<<dim3(CEMB / 128, MROWS / 128), 256, 0, stream>>>(attn16, wp16, bproj, out);
}

// Round 9
// 275.973 us; speedup vs baseline: 1.5702x; 1.5702x over previous
//
#include <hip/hip_runtime.h>
#include <math.h>

#define BATCH 4
#define TSEQ  2048
#define CEMB  1024
#define NHEAD 16
#define HD    64
#define MROWS (BATCH * TSEQ)   // 8192
#define QSCALE 11.5415603271f  // 8 * log2(e): softmax runs in exp2 domain

typedef _Float16 half8 __attribute__((ext_vector_type(8)));
typedef _Float16 half4 __attribute__((ext_vector_type(4)));
typedef _Float16 half2 __attribute__((ext_vector_type(2)));
typedef float    floatx4 __attribute__((ext_vector_type(4)));

#define GLOBAL_AS __attribute__((address_space(1)))
#define LDS_AS    __attribute__((address_space(3)))

__device__ __forceinline__ void lds_dma16(const _Float16* g, _Float16* l) {
    __builtin_amdgcn_global_load_lds((const GLOBAL_AS unsigned int*)g,
                                     (LDS_AS unsigned int*)l, 16, 0, 0);
}

// raw v_exp_f32 (2^x). VALU interlocks handle the hazard; exp2(-inf)=0.
__device__ __forceinline__ float fast_exp2(float x) {
    float r; asm("v_exp_f32 %0, %1" : "=v"(r) : "v"(x)); return r;
}

// packed f32->f16 conversion: 2 v_cvt_pkrtz instead of ~6 cvt+pack ops.
__device__ __forceinline__ half4 pack4(float a0, float a1, float a2, float a3) {
    half2 lo = __builtin_bit_cast(half2, __builtin_amdgcn_cvt_pkrtz(a0, a1));
    half2 hi = __builtin_bit_cast(half2, __builtin_amdgcn_cvt_pkrtz(a2, a3));
    return (half4){lo[0], lo[1], hi[0], hi[1]};
}

// ---------------------------------------------------------------------------
// Kernel 0: fp32 -> fp16 convert prepass (float4 -> half4)
// ---------------------------------------------------------------------------
__global__ __launch_bounds__(256)
void cvt_fp16(const float* __restrict__ x, const float* __restrict__ wa,
              const float* __restrict__ wp, _Float16* __restrict__ x16,
              _Float16* __restrict__ wa16, _Float16* __restrict__ wp16)
{
    const int n1 = (BATCH * TSEQ * CEMB) / 4;
    const int n2 = (3 * CEMB * CEMB) / 4;
    int i = blockIdx.x * 256 + threadIdx.x;
    const float* src; _Float16* dst; int j;
    if (i < n1)            { src = x;  dst = x16;  j = i; }
    else if (i < n1 + n2)  { src = wa; dst = wa16; j = i - n1; }
    else                   { src = wp; dst = wp16; j = i - n1 - n2; }
    float4 v = ((const float4*)src)[j];
    half4 h = { (_Float16)v.x, (_Float16)v.y, (_Float16)v.z, (_Float16)v.w };
    ((half4*)dst)[j] = h;
}

// ---------------------------------------------------------------------------
// GEMM staging: 128x32 fp16 tile, DMA, XOR swizzle c = pc ^ (row&3).
// ---------------------------------------------------------------------------
__device__ __forceinline__ void stage32(const _Float16* __restrict__ gbase,
                                        _Float16* __restrict__ lds,
                                        int row0, int kk, int tid)
{
#pragma unroll
    for (int p = 0; p < 2; ++p) {
        int ci  = p * 256 + tid;
        int row = ci >> 2, pcc = ci & 3;
        int c   = pcc ^ (row & 3);
        lds_dma16(gbase + (size_t)(row0 + row) * CEMB + kk + c * 8, lds + ci * 8);
    }
}

// ---------------------------------------------------------------------------
// Kernel 1: qkv = x16 @ Wa16^T. Epilogue stages C through LDS for coalesced
// half8 stores; v blocks transpose in LDS. q is pre-scaled by 8*log2e.
// XCD swizzle (T1, kept from R8: non-attn time 191->177us): each XCD owns 8
// fixed A row-panels (2MB, L2-resident, read 24x each); 8 consecutive
// blocks per XCD share one B panel (256KB).
// ---------------------------------------------------------------------------
__global__ __launch_bounds__(256)
void qkv_gemm(const _Float16* __restrict__ A, const _Float16* __restrict__ B,
              _Float16* __restrict__ q16, _Float16* __restrict__ k16,
              _Float16* __restrict__ v16)
{
    __shared__ __align__(16) _Float16 smem[16384];   // 32 KB: dbuf tiles / C-tile
    const int tid = threadIdx.x, lane = tid & 63, wave = tid >> 6;
    const int wm = wave & 1, wn = wave >> 1;
    const int L  = blockIdx.x + 24 * blockIdx.y;     // 0..1535
    const int jj = L >> 3;
    const int m0 = ((L & 7) + 8 * (jj & 7)) * 128;
    const int n0 = (jj >> 3) * 128;
    const int l15 = lane & 15, quad = lane >> 4;

    floatx4 acc[4][4];
#pragma unroll
    for (int i = 0; i < 4; ++i)
#pragma unroll
        for (int j = 0; j < 4; ++j) acc[i][j] = (floatx4){0.f, 0.f, 0.f, 0.f};

    stage32(A, smem, m0, 0, tid);
    stage32(B, smem + 8192, n0, 0, tid);
    for (int kt = 0; kt < 32; ++kt) {
        const int cur = kt & 1;
        _Float16* Asc = smem + cur * 4096;
        _Float16* Bsc = smem + 8192 + cur * 4096;
        __syncthreads();                      // drains DMA(kt)
        if (kt < 31) {
            stage32(A, smem + (cur ^ 1) * 4096, m0, (kt + 1) * 32, tid);
            stage32(B, smem + 8192 + (cur ^ 1) * 4096, n0, (kt + 1) * 32, tid);
        }
        half8 af[4], bf[4];
#pragma unroll
        for (int mt = 0; mt < 4; ++mt) {
            int row = wm * 64 + mt * 16 + l15;
            af[mt] = *(const half8*)(Asc + row * 32 + (quad ^ (row & 3)) * 8);
        }
#pragma unroll
        for (int nt = 0; nt < 4; ++nt) {
            int row = wn * 64 + nt * 16 + l15;
            bf[nt] = *(const half8*)(Bsc + row * 32 + (quad ^ (row & 3)) * 8);
        }
#pragma unroll
        for (int mt = 0; mt < 4; ++mt)
#pragma unroll
            for (int nt = 0; nt < 4; ++nt)
                acc[mt][nt] = __builtin_amdgcn_mfma_f32_16x16x32_f16(af[mt], bf[nt], acc[mt][nt], 0, 0, 0);
    }

    __syncthreads();                          // all frag reads done; reuse smem
    const int rbase = quad << 2;
    if (n0 < 2 * CEMB) {
        // --- q/k: C[t][n'] with chunk swizzle pc = (n>>3) ^ (t&15) ---
        const float scale = (n0 < CEMB) ? QSCALE : 1.0f;
#pragma unroll
        for (int mt = 0; mt < 4; ++mt)
#pragma unroll
            for (int nt = 0; nt < 4; ++nt)
#pragma unroll
                for (int r = 0; r < 4; ++r) {
                    int t = wm * 64 + mt * 16 + rbase + r;
                    int n = wn * 64 + nt * 16 + l15;
                    int pc = (n >> 3) ^ (t & 15);
                    smem[t * 128 + pc * 8 + (n & 7)] = (_Float16)(acc[mt][nt][r] * scale);
                }
        __syncthreads();
        const int chunk = tid & 7;
#pragma unroll
        for (int i = 0; i < 8; ++i) {
            int gr = (tid >> 3) + i * 32;     // 0..255: (seg,t)
            int seg = gr >> 7, t = gr & 127;
            int pc = (seg * 8 + chunk) ^ (t & 15);
            half8 v = *(const half8*)(smem + t * 128 + pc * 8);
            int gm = m0 + t, b = gm >> 11, tt = gm & (TSEQ - 1);
            int gnb = n0 + seg * 64;
            _Float16* dst;
            if (n0 < CEMB) {
                int h = gnb >> 6;
                dst = q16 + (((size_t)(b * NHEAD + h)) * TSEQ + tt) * HD;
            } else {
                int h = (gnb - CEMB) >> 6;
                dst = k16 + (((size_t)(b * NHEAD + h)) * TSEQ + tt) * HD;
            }
            *(half8*)(dst + chunk * 8) = v;
        }
    } else {
        // --- v: transpose in LDS: C[n'][t] with pc = (t>>3) ^ (n&15) ---
#pragma unroll
        for (int mt = 0; mt < 4; ++mt)
#pragma unroll
            for (int nt = 0; nt < 4; ++nt)
#pragma unroll
                for (int r = 0; r < 4; ++r) {
                    int t = wm * 64 + mt * 16 + rbase + r;
                    int n = wn * 64 + nt * 16 + l15;
                    int pc = (t >> 3) ^ (n & 15);
                    smem[n * 128 + pc * 8 + (t & 7)] = (_Float16)acc[mt][nt][r];
                }
        __syncthreads();
        const int chunk = tid & 15;           // 16 chunks of 8 along t
        const int b = m0 >> 11, tblk = m0 & (TSEQ - 1);
#pragma unroll
        for (int i = 0; i < 8; ++i) {
            int row = (tid >> 4) + i * 16;    // n' 0..127
            int pc = chunk ^ (row & 15);
            half8 v = *(const half8*)(smem + row * 128 + pc * 8);
            int c2 = n0 - 2 * CEMB + row;
            int h = c2 >> 6, d = c2 & 63;
            *(half8*)(v16 + (((size_t)(b * NHEAD + h)) * HD + d) * TSEQ + tblk + chunk * 8) = v;
        }
    }
}

// ---------------------------------------------------------------------------
// Kernel 2: flash attention — EXACT R6 form (measured 90.4us). V staged in
// LDS via coalesced DMA (R8's direct-L2 V reads were stride-4KB uncoalesced:
// 16 cache lines per load instr, MfmaUtil 23->8, 90->256us. REVERTED).
// S^T = K·Q^T; P in registers (B-layout) for mfma_16x16x16f16. Cooperative:
// 4 waves share each tile; phase 1 = A+B shared-fragment dual-tile, phase 2
// B-only. R2 XCD remap + defer-max + per-lane l partials + pkrtz.
// ---------------------------------------------------------------------------
__device__ __forceinline__ void attn_tile(
    const half8& qf0, const half8& qf1,
    float& m_i, float& l_i, floatx4 (&o)[4],
    const _Float16* __restrict__ Ks, const _Float16* __restrict__ Vs,
    bool domask, int l15, int quad, int relq)
{
    floatx4 s[4];
#pragma unroll
    for (int nt = 0; nt < 4; ++nt) {
        int row = nt * 16 + l15;
        int pc0 = quad ^ (row & 7);
        half8 kf0 = *(const half8*)(Ks + row * 64 + pc0 * 8);
        half8 kf1 = *(const half8*)(Ks + row * 64 + (pc0 ^ 4) * 8);
        floatx4 z = (floatx4){0.f, 0.f, 0.f, 0.f};
        z = __builtin_amdgcn_mfma_f32_16x16x32_f16(kf0, qf0, z, 0, 0, 0);
        z = __builtin_amdgcn_mfma_f32_16x16x32_f16(kf1, qf1, z, 0, 0, 0);
        s[nt] = z;
    }
    if (domask) {
#pragma unroll
        for (int nt = 0; nt < 4; ++nt)
#pragma unroll
            for (int r = 0; r < 4; ++r)
                if (nt * 16 + quad * 4 + r > relq) s[nt][r] = -INFINITY;
    }
    float pmax = -INFINITY;
#pragma unroll
    for (int nt = 0; nt < 4; ++nt)
        pmax = fmaxf(pmax, fmaxf(fmaxf(s[nt][0], s[nt][1]), fmaxf(s[nt][2], s[nt][3])));
    // defer-max: reduce + rescale only if some lane's max grew (else alpha==1)
    if (!__all(pmax <= m_i)) {
        float mx = fmaxf(m_i, pmax);
        mx = fmaxf(mx, __shfl_xor(mx, 16, 64));
        mx = fmaxf(mx, __shfl_xor(mx, 32, 64));
        float alpha = fast_exp2(m_i - mx);
        m_i = mx;
        l_i *= alpha;
#pragma unroll
        for (int mt = 0; mt < 4; ++mt)
#pragma unroll
            for (int r = 0; r < 4; ++r) o[mt][r] *= alpha;
    }
    float rs = 0.f;
    half4 p[4];
#pragma unroll
    for (int nt = 0; nt < 4; ++nt) {
        float p0 = fast_exp2(s[nt][0] - m_i), p1 = fast_exp2(s[nt][1] - m_i);
        float p2 = fast_exp2(s[nt][2] - m_i), p3 = fast_exp2(s[nt][3] - m_i);
        rs += (p0 + p1) + (p2 + p3);
        p[nt] = pack4(p0, p1, p2, p3);
    }
    l_i += rs;   // per-lane partial; reduced once in epilogue
#pragma unroll
    for (int mt = 0; mt < 4; ++mt) {
        int d = mt * 16 + l15;
#pragma unroll
        for (int nt = 0; nt < 4; ++nt) {
            int pc = (2 * nt + (quad >> 1)) ^ (d & 7);
            half4 vf = *(const half4*)(Vs + d * 64 + pc * 8 + (quad & 1) * 4);
            o[mt] = __builtin_amdgcn_mfma_f32_16x16x16f16(vf, p[nt], o[mt], 0, 0, 0);
        }
    }
}

// dual-tile body: A and B interleaved, shared K/V fragments. B never masked
// here (kt <= qtA < qtB); A masked iff kt == qtA.
__device__ __forceinline__ void attn_tile2(
    const half8& qA0, const half8& qA1, const half8& qB0, const half8& qB1,
    float& mAi, float& lAi, floatx4 (&oA)[4],
    float& mBi, float& lBi, floatx4 (&oB)[4],
    const _Float16* __restrict__ Ks, const _Float16* __restrict__ Vs,
    bool maskA, int l15, int quad, int relq)
{
    floatx4 sA[4], sB[4];
#pragma unroll
    for (int nt = 0; nt < 4; ++nt) {
        int row = nt * 16 + l15;
        int pc0 = quad ^ (row & 7);
        half8 kf0 = *(const half8*)(Ks + row * 64 + pc0 * 8);
        half8 kf1 = *(const half8*)(Ks + row * 64 + (pc0 ^ 4) * 8);
        floatx4 zA = (floatx4){0.f, 0.f, 0.f, 0.f};
        floatx4 zB = (floatx4){0.f, 0.f, 0.f, 0.f};
        zA = __builtin_amdgcn_mfma_f32_16x16x32_f16(kf0, qA0, zA, 0, 0, 0);
        zB = __builtin_amdgcn_mfma_f32_16x16x32_f16(kf0, qB0, zB, 0, 0, 0);
        zA = __builtin_amdgcn_mfma_f32_16x16x32_f16(kf1, qA1, zA, 0, 0, 0);
        zB = __builtin_amdgcn_mfma_f32_16x16x32_f16(kf1, qB1, zB, 0, 0, 0);
        sA[nt] = zA; sB[nt] = zB;
    }
    if (maskA) {
#pragma unroll
        for (int nt = 0; nt < 4; ++nt)
#pragma unroll
            for (int r = 0; r < 4; ++r)
                if (nt * 16 + quad * 4 + r > relq) sA[nt][r] = -INFINITY;
    }
    // per-lane maxes (two independent chains)
    float pA = -INFINITY, pB = -INFINITY;
#pragma unroll
    for (int nt = 0; nt < 4; ++nt) {
        pA = fmaxf(pA, fmaxf(fmaxf(sA[nt][0], sA[nt][1]), fmaxf(sA[nt][2], sA[nt][3])));
        pB = fmaxf(pB, fmaxf(fmaxf(sB[nt][0], sB[nt][1]), fmaxf(sB[nt][2], sB[nt][3])));
    }
    if (!__all((pA <= mAi) && (pB <= mBi))) {
        float mxA = fmaxf(mAi, pA), mxB = fmaxf(mBi, pB);
        mxA = fmaxf(mxA, __shfl_xor(mxA, 16, 64));
        mxB = fmaxf(mxB, __shfl_xor(mxB, 16, 64));
        mxA = fmaxf(mxA, __shfl_xor(mxA, 32, 64));
        mxB = fmaxf(mxB, __shfl_xor(mxB, 32, 64));
        float alA = fast_exp2(mAi - mxA);
        float alB = fast_exp2(mBi - mxB);
        mAi = mxA; mBi = mxB;
        lAi *= alA; lBi *= alB;
#pragma unroll
        for (int mt = 0; mt < 4; ++mt)
#pragma unroll
            for (int r = 0; r < 4; ++r) { oA[mt][r] *= alA; oB[mt][r] *= alB; }
    }
    float rsA = 0.f, rsB = 0.f;
    half4 pAh[4], pBh[4];
#pragma unroll
    for (int nt = 0; nt < 4; ++nt) {
        float a0 = fast_exp2(sA[nt][0] - mAi), b0 = fast_exp2(sB[nt][0] - mBi);
        float a1 = fast_exp2(sA[nt][1] - mAi), b1 = fast_exp2(sB[nt][1] - mBi);
        float a2 = fast_exp2(sA[nt][2] - mAi), b2 = fast_exp2(sB[nt][2] - mBi);
        float a3 = fast_exp2(sA[nt][3] - mAi), b3 = fast_exp2(sB[nt][3] - mBi);
        rsA += (a0 + a1) + (a2 + a3);
        rsB += (b0 + b1) + (b2 + b3);
        pAh[nt] = pack4(a0, a1, a2, a3);
        pBh[nt] = pack4(b0, b1, b2, b3);
    }
    lAi += rsA; lBi += rsB;   // per-lane partials
    // PV with shared V fragments
#pragma unroll
    for (int mt = 0; mt < 4; ++mt) {
        int d = mt * 16 + l15;
#pragma unroll
        for (int nt = 0; nt < 4; ++nt) {
            int pc = (2 * nt + (quad >> 1)) ^ (d & 7);
            half4 vf = *(const half4*)(Vs + d * 64 + pc * 8 + (quad & 1) * 4);
            oA[mt] = __builtin_amdgcn_mfma_f32_16x16x16f16(vf, pAh[nt], oA[mt], 0, 0, 0);
            oB[mt] = __builtin_amdgcn_mfma_f32_16x16x16f16(vf, pBh[nt], oB[mt], 0, 0, 0);
        }
    }
}

__global__ __launch_bounds__(256)
void attn_fwd(const _Float16* __restrict__ q16, const _Float16* __restrict__ k16,
              const _Float16* __restrict__ v16, _Float16* __restrict__ o16)
{
    __shared__ __align__(16) _Float16 Ks[2][64 * 64];
    __shared__ __align__(16) _Float16 Vs[2][64 * 64];
    const int tid = threadIdx.x, lane = tid & 63, wave = tid >> 6;
    const int l15 = lane & 15, quad = lane >> 4;

    // R2 remap (measured best): each XCD owns 8 bh -> K/V L2-resident
    // (FETCH 128MB -> 25MB measured).
    const int L   = blockIdx.x + 16 * blockIdx.y;
    const int qtA = (L >> 3) & 15;             // 0..15
    const int bh  = (L & 7) + ((L >> 7) << 3); // 0..63
    const int qtB = 31 - qtA;                  // 16..31
    const int b = bh >> 4, h = bh & 15;
    const int q0A = qtA * 64, q0B = qtB * 64;
    const _Float16* qp = q16 + (size_t)bh * TSEQ * HD;
    const _Float16* kp = k16 + (size_t)bh * TSEQ * HD;
    const _Float16* vp = v16 + (size_t)bh * HD * TSEQ;

    const int relq = wave * 16 + l15;
    half8 qA0 = *(const half8*)(qp + (size_t)(q0A + relq) * HD + quad * 8);
    half8 qA1 = *(const half8*)(qp + (size_t)(q0A + relq) * HD + 32 + quad * 8);
    half8 qB0 = *(const half8*)(qp + (size_t)(q0B + relq) * HD + quad * 8);
    half8 qB1 = *(const half8*)(qp + (size_t)(q0B + relq) * HD + 32 + quad * 8);

    float mA = -INFINITY, lA = 0.f, mB = -INFINITY, lB = 0.f;
    floatx4 oA[4], oB[4];
#pragma unroll
    for (int mt = 0; mt < 4; ++mt) { oA[mt] = (floatx4){0.f,0.f,0.f,0.f}; oB[mt] = (floatx4){0.f,0.f,0.f,0.f}; }

#define STAGE_KV(kt0, buf)                                                     \
    {                                                                          \
        _Float16* kd = Ks[buf];                                                \
        _Float16* vd = Vs[buf];                                                \
        _Pragma("unroll")                                                      \
        for (int p = 0; p < 2; ++p) {                                          \
            int ci = p * 256 + tid;                                            \
            int row = ci >> 3;                                                 \
            int c2 = (ci & 7) ^ (row & 7);                                     \
            lds_dma16(kp + (size_t)((kt0) + row) * HD + c2 * 8, kd + ci * 8);  \
            lds_dma16(vp + (size_t)row * TSEQ + (kt0) + c2 * 8, vd + ci * 8);  \
        }                                                                      \
    }

    STAGE_KV(0, 0);
    // phase 1: kt = 0..qtA — both tiles, shared K/V frags, interleaved ILP
    for (int kt = 0; kt <= qtA; ++kt) {
        const int cur = kt & 1;
        __syncthreads();
        STAGE_KV((kt + 1) * 64, cur ^ 1);     // kt+1 <= qtA+1 <= qtB: valid
        attn_tile2(qA0, qA1, qB0, qB1, mA, lA, oA, mB, lB, oB,
                   Ks[cur], Vs[cur], (kt == qtA), l15, quad, relq);
    }
    // phase 2: kt = qtA+1..qtB — B only
    for (int kt = qtA + 1; kt <= qtB; ++kt) {
        const int cur = kt & 1;
        __syncthreads();
        if (kt < qtB) STAGE_KV((kt + 1) * 64, cur ^ 1);
        attn_tile(qB0, qB1, mB, lB, oB, Ks[cur], Vs[cur], (kt == qtB), l15, quad, relq);
    }
#undef STAGE_KV

    // reduce per-lane l partials across the 4 lanes sharing each q-row
    lA += __shfl_xor(lA, 16, 64); lA += __shfl_xor(lA, 32, 64);
    lB += __shfl_xor(lB, 16, 64); lB += __shfl_xor(lB, 32, 64);
    const float invA = 1.f / lA, invB = 1.f / lB;
    const size_t baseA = ((size_t)(b * TSEQ + q0A + relq)) * CEMB + h * HD + quad * 4;
    const size_t baseB = ((size_t)(b * TSEQ + q0B + relq)) * CEMB + h * HD + quad * 4;
#pragma unroll
    for (int mt = 0; mt < 4; ++mt) {
        half4 ha = { (_Float16)(oA[mt][0] * invA), (_Float16)(oA[mt][1] * invA),
                     (_Float16)(oA[mt][2] * invA), (_Float16)(oA[mt][3] * invA) };
        half4 hb = { (_Float16)(oB[mt][0] * invB), (_Float16)(oB[mt][1] * invB),
                     (_Float16)(oB[mt][2] * invB), (_Float16)(oB[mt][3] * invB) };
        *(half4*)(o16 + baseA + mt * 16) = ha;
        *(half4*)(o16 + baseB + mt * 16) = hb;
    }
}

// ---------------------------------------------------------------------------
// Kernel 3: y = attn16 @ Wp16^T + b_proj, fp32 out. 128x128 tile, 512
// blocks (grid (8,64) — L in [0,512)). XCD swizzle kept from R8: each XCD
// owns 8 A row-panels (2MB) + full Wp (2MB) = L2-sized.
// ---------------------------------------------------------------------------
__global__ __launch_bounds__(256)
void proj_gemm(const _Float16* __restrict__ A, const _Float16* __restrict__ B,
               const float* __restrict__ bias, float* __restrict__ out)
{
    __shared__ __align__(16) _Float16 smem[16384];   // 32 KB dbuf tiles
    const int tid = threadIdx.x, lane = tid & 63, wave = tid >> 6;
    const int wm = wave & 1, wn = wave >> 1;
    const int L  = blockIdx.x + 8 * blockIdx.y;      // 0..511
    const int jj = L >> 3;                            // 0..63
    const int m0 = ((L & 7) + 8 * (jj & 7)) * 128;   // XCD's 8 panels
    const int n0 = (jj >> 3) * 128;                  // 0..7 panels
    const int l15 = lane & 15, quad = lane >> 4;

    floatx4 acc[4][4];
#pragma unroll
    for (int i = 0; i < 4; ++i)
#pragma unroll
        for (int j = 0; j < 4; ++j) acc[i][j] = (floatx4){0.f, 0.f, 0.f, 0.f};

    stage32(A, smem, m0, 0, tid);
    stage32(B, smem + 8192, n0, 0, tid);
    for (int kt = 0; kt < 32; ++kt) {
        const int cur = kt & 1;
        _Float16* Asc = smem + cur * 4096;
        _Float16* Bsc = smem + 8192 + cur * 4096;
        __syncthreads();                      // drains DMA(kt)
        if (kt < 31) {
            stage32(A, smem + (cur ^ 1) * 4096, m0, (kt + 1) * 32, tid);
            stage32(B, smem + 8192 + (cur ^ 1) * 4096, n0, (kt + 1) * 32, tid);
        }
        half8 af[4], bf[4];
#pragma unroll
        for (int mt = 0; mt < 4; ++mt) {
            int row = wm * 64 + mt * 16 + l15;
            af[mt] = *(const half8*)(Asc + row * 32 + (quad ^ (row & 3)) * 8);
        }
#pragma unroll
        for (int nt = 0; nt < 4; ++nt) {
            int row = wn * 64 + nt * 16 + l15;
            bf[nt] = *(const half8*)(Bsc + row * 32 + (quad ^ (row & 3)) * 8);
        }
#pragma unroll
        for (int mt = 0; mt < 4; ++mt)
#pragma unroll
            for (int nt = 0; nt < 4; ++nt)
                acc[mt][nt] = __builtin_amdgcn_mfma_f32_16x16x32_f16(af[mt], bf[nt], acc[mt][nt], 0, 0, 0);
    }

    const int rbase = quad << 2;
#pragma unroll
    for (int mt = 0; mt < 4; ++mt)
#pragma unroll
        for (int nt = 0; nt < 4; ++nt) {
            int gn = n0 + wn * 64 + nt * 16 + l15;
            float bb = bias[gn];
#pragma unroll
            for (int r = 0; r < 4; ++r) {
                int gm = m0 + wm * 64 + mt * 16 + rbase + r;
                out[(size_t)gm * CEMB + gn] = acc[mt][nt][r] + bb;
            }
        }
}

// ---------------------------------------------------------------------------
extern "C" void kernel_launch(void* const* d_in, const int* in_sizes, int n_in,
                              void* d_out, int out_size, void* d_ws, size_t ws_size,
                              hipStream_t stream) {
    const float* x     = (const float*)d_in[0];
    const float* Wattn = (const float*)d_in[1];
    const float* Wproj = (const float*)d_in[2];
    const float* bproj = (const float*)d_in[3];
    float* out = (float*)d_out;

    const size_t nx  = (size_t)BATCH * TSEQ * CEMB;
    const size_t nwa = (size_t)3 * CEMB * CEMB;
    const size_t nwp = (size_t)CEMB * CEMB;
    const size_t per = (size_t)BATCH * NHEAD * TSEQ * HD;

    _Float16* x16    = (_Float16*)d_ws;
    _Float16* wa16   = x16 + nx;
    _Float16* wp16   = wa16 + nwa;
    _Float16* q16    = wp16 + nwp;
    _Float16* k16    = q16 + per;
    _Float16* v16    = k16 + per;
    _Float16* attn16 = x16;   // alias: x16 fully consumed before attn writes

    const int nconv = (int)((nx + nwa + nwp) / 4);
    cvt_fp16<<<nconv / 256, 256, 0, stream>>>(x, Wattn, Wproj, x16, wa16, wp16);
    qkv_gemm<<<dim3(3 * CEMB / 128, MROWS / 128), 256, 0, stream>>>(x16, wa16, q16, k16, v16);
    attn_fwd<<<dim3(16, BATCH * NHEAD), 256, 0, stream>>>(q16, k16, v16, attn16);
    proj_gemm<<<dim3(CEMB / 128, MROWS / 128), 256, 0, stream>>>(attn16, wp16, bproj, out);
}

// Round 11
// 270.000 us; speedup vs baseline: 1.6049x; 1.0221x over previous
//
#include <hip/hip_runtime.h>
#include <math.h>

#define BATCH 4
#define TSEQ  2048
#define CEMB  1024
#define NHEAD 16
#define HD    64
#define MROWS (BATCH * TSEQ)   // 8192
#define QSCALE 11.5415603271f  // 8 * log2(e): softmax runs in exp2 domain

typedef _Float16 half8 __attribute__((ext_vector_type(8)));
typedef _Float16 half4 __attribute__((ext_vector_type(4)));
typedef _Float16 half2 __attribute__((ext_vector_type(2)));
typedef float    floatx4 __attribute__((ext_vector_type(4)));

#define GLOBAL_AS __attribute__((address_space(1)))
#define LDS_AS    __attribute__((address_space(3)))

__device__ __forceinline__ void lds_dma16(const _Float16* g, _Float16* l) {
    __builtin_amdgcn_global_load_lds((const GLOBAL_AS unsigned int*)g,
                                     (LDS_AS unsigned int*)l, 16, 0, 0);
}

// raw v_exp_f32 (2^x). VALU interlocks handle the hazard; exp2(-inf)=0.
__device__ __forceinline__ float fast_exp2(float x) {
    float r; asm("v_exp_f32 %0, %1" : "=v"(r) : "v"(x)); return r;
}

// packed f32->f16 conversion: 2 v_cvt_pkrtz instead of ~6 cvt+pack ops.
__device__ __forceinline__ half4 pack4(float a0, float a1, float a2, float a3) {
    half2 lo = __builtin_bit_cast(half2, __builtin_amdgcn_cvt_pkrtz(a0, a1));
    half2 hi = __builtin_bit_cast(half2, __builtin_amdgcn_cvt_pkrtz(a2, a3));
    return (half4){lo[0], lo[1], hi[0], hi[1]};
}

// ---------------------------------------------------------------------------
// Kernel 0: fp32 -> fp16 convert prepass (float4 -> half4)
// ---------------------------------------------------------------------------
__global__ __launch_bounds__(256)
void cvt_fp16(const float* __restrict__ x, const float* __restrict__ wa,
              const float* __restrict__ wp, _Float16* __restrict__ x16,
              _Float16* __restrict__ wa16, _Float16* __restrict__ wp16)
{
    const int n1 = (BATCH * TSEQ * CEMB) / 4;
    const int n2 = (3 * CEMB * CEMB) / 4;
    int i = blockIdx.x * 256 + threadIdx.x;
    const float* src; _Float16* dst; int j;
    if (i < n1)            { src = x;  dst = x16;  j = i; }
    else if (i < n1 + n2)  { src = wa; dst = wa16; j = i - n1; }
    else                   { src = wp; dst = wp16; j = i - n1 - n2; }
    float4 v = ((const float4*)src)[j];
    half4 h = { (_Float16)v.x, (_Float16)v.y, (_Float16)v.z, (_Float16)v.w };
    ((half4*)dst)[j] = h;
}

// ---------------------------------------------------------------------------
// GEMM staging helpers. XOR swizzle chunk = pc ^ (row & mask); reads undo it.
// ---------------------------------------------------------------------------
__device__ __forceinline__ void stage32(const _Float16* __restrict__ gbase,
                                        _Float16* __restrict__ lds,
                                        int row0, int kk, int tid)
{
#pragma unroll
    for (int p = 0; p < 2; ++p) {
        int ci  = p * 256 + tid;
        int row = ci >> 2, pcc = ci & 3;
        int c   = pcc ^ (row & 3);
        lds_dma16(gbase + (size_t)(row0 + row) * CEMB + kk + c * 8, lds + ci * 8);
    }
}

// 128 rows x 64 cols half-tile, 512 threads, 2 DMA/thread, 8-chunk XOR swizzle
__device__ __forceinline__ void stage_half(const _Float16* __restrict__ g,
                                           _Float16* __restrict__ lds,
                                           int row0, int kk, int tid)
{
#pragma unroll
    for (int p = 0; p < 2; ++p) {
        int ci  = p * 512 + tid;          // 0..1023
        int row = ci >> 3;
        int c   = (ci & 7) ^ (row & 7);
        lds_dma16(g + (size_t)(row0 + row) * CEMB + kk + c * 8, lds + ci * 8);
    }
}

// ---------------------------------------------------------------------------
// Kernel 1a: q,k = x16 @ Wa16^T (N = 0..2047). 8-phase 256x256 schedule
// (T2+T3+T4+T5): BK=64, 8 waves (2M x 4N), per-wave 128x64 output, 128KB LDS.
// vmcnt(4) INSIDE phases 4/8, after MFMA and BEFORE the end-barrier: vmcnt
// is per-wave, so the following barrier is what makes "my DMAs landed" into
// "all DMAs landed" before any wave reads the new tile (R10 bug #2 fixed).
// Last iteration peeled with vmcnt(0) (guarded-out stages would leave A(15)
// outside the vmcnt(4) window — R10 bug #3 fixed).
// 256 blocks = 1/CU exactly. Epilogue restages C in LDS for half8 stores.
// ---------------------------------------------------------------------------
__global__ __launch_bounds__(512, 2)
void qk_gemm(const _Float16* __restrict__ A, const _Float16* __restrict__ B,
             _Float16* __restrict__ q16, _Float16* __restrict__ k16)
{
    __shared__ __align__(16) _Float16 smem[65536];   // 128 KB
    const int tid = threadIdx.x, lane = tid & 63, wv = tid >> 6;
    const int wm = wv & 1, wn = wv >> 1;             // 2 x 4 waves
    const int l15 = lane & 15, quad = lane >> 4;

    // XCD map: L%8 = xcd; each XCD owns 4 m-panels (2MB A L2-resident).
    const int L  = blockIdx.x + 8 * blockIdx.y;      // 0..255
    const int m0 = ((L & 7) * 4 + ((L >> 3) & 3)) * 256;  // 0..31 panels
    const int n0 = (L >> 5) * 256;                   // 0..7 panels (q:0-3 k:4-7)

    floatx4 acc[8][4];
#pragma unroll
    for (int i = 0; i < 8; ++i)
#pragma unroll
        for (int j = 0; j < 4; ++j) acc[i][j] = (floatx4){0.f, 0.f, 0.f, 0.f};

    // LDS slots (halves): A(buf,half) = (buf*2+half)*8192 ; B same + 32768
#define STG_A(t, hf) stage_half(A, smem + (((t)&1)*2 + (hf))*8192, m0 + (hf)*128, (t)*64, tid)
#define STG_B(t, hf) stage_half(B, smem + 32768 + (((t)&1)*2 + (hf))*8192, n0 + (hf)*128, (t)*64, tid)
#define NOSTG ((void)0)
#define WAIT4 asm volatile("s_waitcnt vmcnt(4)" ::: "memory")
#define WAIT0 asm volatile("s_waitcnt vmcnt(0)" ::: "memory")
#define NOWAIT ((void)0)

    // prologue: tile0 A+B, tile1 B. vmcnt(4) => tile0 fully landed; barrier
    // promotes per-wave guarantee to all-waves.
    STG_B(0, 0); STG_B(0, 1); STG_A(0, 0); STG_A(0, 1);
    STG_B(1, 0); STG_B(1, 1);
    WAIT4;
    __builtin_amdgcn_s_barrier();

    // phase: quadrant qd of tile t. bfr loaded at qd==0, persists 4 phases.
    // WAIT_STMT sits after MFMA, BEFORE the end-barrier.
#define PHASE(t, qd, STAGE_STMT, WAIT_STMT)                                   \
    {                                                                         \
        const _Float16* Ab = smem + (((t)&1)*2 + wm) * 8192;                  \
        const _Float16* Bb = smem + 32768 + (((t)&1)*2 + (wn >> 1)) * 8192;   \
        half8 af[2][2];                                                       \
        _Pragma("unroll")                                                     \
        for (int i = 0; i < 2; ++i) {                                         \
            int row = ((qd)*2 + i)*16 + l15;                                  \
            _Pragma("unroll")                                                 \
            for (int ks = 0; ks < 2; ++ks)                                    \
                af[i][ks] = *(const half8*)(Ab + row*64 + (((ks*4 + quad) ^ (row & 7)) << 3)); \
        }                                                                     \
        if ((qd) == 0) {                                                      \
            _Pragma("unroll")                                                 \
            for (int ni = 0; ni < 4; ++ni) {                                  \
                int row = (wn & 1)*64 + ni*16 + l15;                          \
                _Pragma("unroll")                                             \
                for (int ks = 0; ks < 2; ++ks)                                \
                    bfr[ni][ks] = *(const half8*)(Bb + row*64 + (((ks*4 + quad) ^ (row & 7)) << 3)); \
            }                                                                 \
        }                                                                     \
        STAGE_STMT;                                                           \
        __builtin_amdgcn_s_barrier();                                         \
        __builtin_amdgcn_s_setprio(1);                                        \
        _Pragma("unroll")                                                     \
        for (int i = 0; i < 2; ++i)                                           \
            _Pragma("unroll")                                                 \
            for (int ni = 0; ni < 4; ++ni) {                                  \
                acc[(qd)*2+i][ni] = __builtin_amdgcn_mfma_f32_16x16x32_f16(af[i][0], bfr[ni][0], acc[(qd)*2+i][ni], 0, 0, 0); \
                acc[(qd)*2+i][ni] = __builtin_amdgcn_mfma_f32_16x16x32_f16(af[i][1], bfr[ni][1], acc[(qd)*2+i][ni], 0, 0, 0); \
            }                                                                 \
        __builtin_amdgcn_s_setprio(0);                                        \
        WAIT_STMT;                                                            \
        __builtin_amdgcn_s_barrier();                                         \
    }

    for (int j = 0; j < 7; ++j) {
        const int t0 = 2*j, t1 = 2*j + 1;
        half8 bfr[4][2];
        PHASE(t0, 0, STG_A(t1, 0),     NOWAIT);
        PHASE(t0, 1, STG_A(t1, 1),     NOWAIT);
        PHASE(t0, 2, STG_B(t0 + 2, 0), NOWAIT);
        PHASE(t0, 3, STG_B(t0 + 2, 1), WAIT4);   // B(t1)+A(t1) landed for all
        PHASE(t1, 0, STG_A(t0 + 2, 0), NOWAIT);
        PHASE(t1, 1, STG_A(t0 + 2, 1), NOWAIT);
        PHASE(t1, 2, STG_B(t1 + 2, 0), NOWAIT);
        PHASE(t1, 3, STG_B(t1 + 2, 1), WAIT4);   // B(t0+2)+A(t0+2) landed
    }
    // tail j=7: t0=14, t1=15. Nothing staged for t>=16; drain with vmcnt(0)
    // so A(15) is guaranteed landed (vmcnt(4) would leave exactly 4 = A(15)).
    {
        half8 bfr[4][2];
        PHASE(14, 0, STG_A(15, 0), NOWAIT);
        PHASE(14, 1, STG_A(15, 1), NOWAIT);
        PHASE(14, 2, NOSTG,        NOWAIT);
        PHASE(14, 3, NOSTG,        WAIT0);
        PHASE(15, 0, NOSTG,        NOWAIT);
        PHASE(15, 1, NOSTG,        NOWAIT);
        PHASE(15, 2, NOSTG,        NOWAIT);
        PHASE(15, 3, NOSTG,        NOWAIT);
    }
#undef PHASE
#undef STG_A
#undef STG_B

    // epilogue: restage C (256x256 fp16 = 128KB) for coalesced stores.
    // chunk swizzle pc = (n>>3) ^ (t&31).
    __builtin_amdgcn_s_barrier();
    const float scale = (n0 < CEMB) ? QSCALE : 1.0f;
    const int rbase = quad << 2;
#pragma unroll
    for (int mi = 0; mi < 8; ++mi)
#pragma unroll
        for (int ni = 0; ni < 4; ++ni)
#pragma unroll
            for (int r = 0; r < 4; ++r) {
                int t = wm*128 + mi*16 + rbase + r;
                int n = wn*64 + ni*16 + l15;
                int pc = (n >> 3) ^ (t & 31);
                smem[t*256 + pc*8 + (n & 7)] = (_Float16)(acc[mi][ni][r] * scale);
            }
    asm volatile("s_waitcnt lgkmcnt(0)" ::: "memory");
    __builtin_amdgcn_s_barrier();
    const int chunk = tid & 31;
    _Float16* dstb = (n0 < CEMB) ? q16 : k16;
    const int nbase = n0 - ((n0 < CEMB) ? 0 : CEMB);
#pragma unroll
    for (int i = 0; i < 16; ++i) {
        int t = (tid >> 5) + i*16;          // 0..255
        int pc = chunk ^ (t & 31);
        half8 v = *(const half8*)(smem + t*256 + pc*8);
        int gm = m0 + t, b = gm >> 11, tt = gm & (TSEQ - 1);
        int gn = nbase + chunk*8;
        int h = gn >> 6, d = gn & 63;
        *(half8*)(dstb + (((size_t)(b * NHEAD + h)) * TSEQ + tt) * HD + d) = v;
    }
}

// ---------------------------------------------------------------------------
// Kernel 1b: v = x16 @ Wa16^T (N = 2048..3071). Proven 128x128 2-phase
// structure with the transpose epilogue. 512 blocks = 2/CU, balanced.
// ---------------------------------------------------------------------------
__global__ __launch_bounds__(256)
void v_gemm(const _Float16* __restrict__ A, const _Float16* __restrict__ B,
            _Float16* __restrict__ v16)
{
    __shared__ __align__(16) _Float16 smem[16384];   // 32 KB dbuf tiles
    const int tid = threadIdx.x, lane = tid & 63, wave = tid >> 6;
    const int wm = wave & 1, wn = wave >> 1;
    const int L  = blockIdx.x + 8 * blockIdx.y;      // 0..511
    const int jj = L >> 3;                            // 0..63
    const int m0 = ((L & 7) + 8 * (jj & 7)) * 128;   // 0..63 m-panels
    const int n0 = 2 * CEMB + (jj >> 3) * 128;       // v region
    const int l15 = lane & 15, quad = lane >> 4;

    floatx4 acc[4][4];
#pragma unroll
    for (int i = 0; i < 4; ++i)
#pragma unroll
        for (int j = 0; j < 4; ++j) acc[i][j] = (floatx4){0.f, 0.f, 0.f, 0.f};

    stage32(A, smem, m0, 0, tid);
    stage32(B, smem + 8192, n0, 0, tid);
    for (int kt = 0; kt < 32; ++kt) {
        const int cur = kt & 1;
        _Float16* Asc = smem + cur * 4096;
        _Float16* Bsc = smem + 8192 + cur * 4096;
        __syncthreads();                      // drains DMA(kt)
        if (kt < 31) {
            stage32(A, smem + (cur ^ 1) * 4096, m0, (kt + 1) * 32, tid);
            stage32(B, smem + 8192 + (cur ^ 1) * 4096, n0, (kt + 1) * 32, tid);
        }
        half8 af[4], bf[4];
#pragma unroll
        for (int mt = 0; mt < 4; ++mt) {
            int row = wm * 64 + mt * 16 + l15;
            af[mt] = *(const half8*)(Asc + row * 32 + (quad ^ (row & 3)) * 8);
        }
#pragma unroll
        for (int nt = 0; nt < 4; ++nt) {
            int row = wn * 64 + nt * 16 + l15;
            bf[nt] = *(const half8*)(Bsc + row * 32 + (quad ^ (row & 3)) * 8);
        }
#pragma unroll
        for (int mt = 0; mt < 4; ++mt)
#pragma unroll
            for (int nt = 0; nt < 4; ++nt)
                acc[mt][nt] = __builtin_amdgcn_mfma_f32_16x16x32_f16(af[mt], bf[nt], acc[mt][nt], 0, 0, 0);
    }

    __syncthreads();                          // reuse smem for C
    const int rbase = quad << 2;
#pragma unroll
    for (int mt = 0; mt < 4; ++mt)
#pragma unroll
        for (int nt = 0; nt < 4; ++nt)
#pragma unroll
            for (int r = 0; r < 4; ++r) {
                int t = wm * 64 + mt * 16 + rbase + r;
                int n = wn * 64 + nt * 16 + l15;
                int pc = (t >> 3) ^ (n & 15);
                smem[n * 128 + pc * 8 + (t & 7)] = (_Float16)acc[mt][nt][r];
            }
    __syncthreads();
    const int chunk = tid & 15;               // 16 chunks of 8 along t
    const int b = m0 >> 11, tblk = m0 & (TSEQ - 1);
#pragma unroll
    for (int i = 0; i < 8; ++i) {
        int row = (tid >> 4) + i * 16;        // n' 0..127
        int pc = chunk ^ (row & 15);
        half8 v = *(const half8*)(smem + row * 128 + pc * 8);
        int c2 = n0 - 2 * CEMB + row;
        int h = c2 >> 6, d = c2 & 63;
        *(half8*)(v16 + (((size_t)(b * NHEAD + h)) * HD + d) * TSEQ + tblk + chunk * 8) = v;
    }
}

// ---------------------------------------------------------------------------
// Kernel 2: flash attention — R6/R9 form (measured 90.4us). V staged in LDS
// via coalesced DMA. Cooperative dual-tile + R2 XCD remap + defer-max +
// per-lane l partials + pkrtz.
// ---------------------------------------------------------------------------
__device__ __forceinline__ void attn_tile(
    const half8& qf0, const half8& qf1,
    float& m_i, float& l_i, floatx4 (&o)[4],
    const _Float16* __restrict__ Ks, const _Float16* __restrict__ Vs,
    bool domask, int l15, int quad, int relq)
{
    floatx4 s[4];
#pragma unroll
    for (int nt = 0; nt < 4; ++nt) {
        int row = nt * 16 + l15;
        int pc0 = quad ^ (row & 7);
        half8 kf0 = *(const half8*)(Ks + row * 64 + pc0 * 8);
        half8 kf1 = *(const half8*)(Ks + row * 64 + (pc0 ^ 4) * 8);
        floatx4 z = (floatx4){0.f, 0.f, 0.f, 0.f};
        z = __builtin_amdgcn_mfma_f32_16x16x32_f16(kf0, qf0, z, 0, 0, 0);
        z = __builtin_amdgcn_mfma_f32_16x16x32_f16(kf1, qf1, z, 0, 0, 0);
        s[nt] = z;
    }
    if (domask) {
#pragma unroll
        for (int nt = 0; nt < 4; ++nt)
#pragma unroll
            for (int r = 0; r < 4; ++r)
                if (nt * 16 + quad * 4 + r > relq) s[nt][r] = -INFINITY;
    }
    float pmax = -INFINITY;
#pragma unroll
    for (int nt = 0; nt < 4; ++nt)
        pmax = fmaxf(pmax, fmaxf(fmaxf(s[nt][0], s[nt][1]), fmaxf(s[nt][2], s[nt][3])));
    if (!__all(pmax <= m_i)) {
        float mx = fmaxf(m_i, pmax);
        mx = fmaxf(mx, __shfl_xor(mx, 16, 64));
        mx = fmaxf(mx, __shfl_xor(mx, 32, 64));
        float alpha = fast_exp2(m_i - mx);
        m_i = mx;
        l_i *= alpha;
#pragma unroll
        for (int mt = 0; mt < 4; ++mt)
#pragma unroll
            for (int r = 0; r < 4; ++r) o[mt][r] *= alpha;
    }
    float rs = 0.f;
    half4 p[4];
#pragma unroll
    for (int nt = 0; nt < 4; ++nt) {
        float p0 = fast_exp2(s[nt][0] - m_i), p1 = fast_exp2(s[nt][1] - m_i);
        float p2 = fast_exp2(s[nt][2] - m_i), p3 = fast_exp2(s[nt][3] - m_i);
        rs += (p0 + p1) + (p2 + p3);
        p[nt] = pack4(p0, p1, p2, p3);
    }
    l_i += rs;
#pragma unroll
    for (int mt = 0; mt < 4; ++mt) {
        int d = mt * 16 + l15;
#pragma unroll
        for (int nt = 0; nt < 4; ++nt) {
            int pc = (2 * nt + (quad >> 1)) ^ (d & 7);
            half4 vf = *(const half4*)(Vs + d * 64 + pc * 8 + (quad & 1) * 4);
            o[mt] = __builtin_amdgcn_mfma_f32_16x16x16f16(vf, p[nt], o[mt], 0, 0, 0);
        }
    }
}

__device__ __forceinline__ void attn_tile2(
    const half8& qA0, const half8& qA1, const half8& qB0, const half8& qB1,
    float& mAi, float& lAi, floatx4 (&oA)[4],
    float& mBi, float& lBi, floatx4 (&oB)[4],
    const _Float16* __restrict__ Ks, const _Float16* __restrict__ Vs,
    bool maskA, int l15, int quad, int relq)
{
    floatx4 sA[4], sB[4];
#pragma unroll
    for (int nt = 0; nt < 4; ++nt) {
        int row = nt * 16 + l15;
        int pc0 = quad ^ (row & 7);
        half8 kf0 = *(const half8*)(Ks + row * 64 + pc0 * 8);
        half8 kf1 = *(const half8*)(Ks + row * 64 + (pc0 ^ 4) * 8);
        floatx4 zA = (floatx4){0.f, 0.f, 0.f, 0.f};
        floatx4 zB = (floatx4){0.f, 0.f, 0.f, 0.f};
        zA = __builtin_amdgcn_mfma_f32_16x16x32_f16(kf0, qA0, zA, 0, 0, 0);
        zB = __builtin_amdgcn_mfma_f32_16x16x32_f16(kf0, qB0, zB, 0, 0, 0);
        zA = __builtin_amdgcn_mfma_f32_16x16x32_f16(kf1, qA1, zA, 0, 0, 0);
        zB = __builtin_amdgcn_mfma_f32_16x16x32_f16(kf1, qB1, zB, 0, 0, 0);
        sA[nt] = zA; sB[nt] = zB;
    }
    if (maskA) {
#pragma unroll
        for (int nt = 0; nt < 4; ++nt)
#pragma unroll
            for (int r = 0; r < 4; ++r)
                if (nt * 16 + quad * 4 + r > relq) sA[nt][r] = -INFINITY;
    }
    float pA = -INFINITY, pB = -INFINITY;
#pragma unroll
    for (int nt = 0; nt < 4; ++nt) {
        pA = fmaxf(pA, fmaxf(fmaxf(sA[nt][0], sA[nt][1]), fmaxf(sA[nt][2], sA[nt][3])));
        pB = fmaxf(pB, fmaxf(fmaxf(sB[nt][0], sB[nt][1]), fmaxf(sB[nt][2], sB[nt][3])));
    }
    if (!__all((pA <= mAi) && (pB <= mBi))) {
        float mxA = fmaxf(mAi, pA), mxB = fmaxf(mBi, pB);
        mxA = fmaxf(mxA, __shfl_xor(mxA, 16, 64));
        mxB = fmaxf(mxB, __shfl_xor(mxB, 16, 64));
        mxA = fmaxf(mxA, __shfl_xor(mxA, 32, 64));
        mxB = fmaxf(mxB, __shfl_xor(mxB, 32, 64));
        float alA = fast_exp2(mAi - mxA);
        float alB = fast_exp2(mBi - mxB);
        mAi = mxA; mBi = mxB;
        lAi *= alA; lBi *= alB;
#pragma unroll
        for (int mt = 0; mt < 4; ++mt)
#pragma unroll
            for (int r = 0; r < 4; ++r) { oA[mt][r] *= alA; oB[mt][r] *= alB; }
    }
    float rsA = 0.f, rsB = 0.f;
    half4 pAh[4], pBh[4];
#pragma unroll
    for (int nt = 0; nt < 4; ++nt) {
        float a0 = fast_exp2(sA[nt][0] - mAi), b0 = fast_exp2(sB[nt][0] - mBi);
        float a1 = fast_exp2(sA[nt][1] - mAi), b1 = fast_exp2(sB[nt][1] - mBi);
        float a2 = fast_exp2(sA[nt][2] - mAi), b2 = fast_exp2(sB[nt][2] - mBi);
        float a3 = fast_exp2(sA[nt][3] - mAi), b3 = fast_exp2(sB[nt][3] - mBi);
        rsA += (a0 + a1) + (a2 + a3);
        rsB += (b0 + b1) + (b2 + b3);
        pAh[nt] = pack4(a0, a1, a2, a3);
        pBh[nt] = pack4(b0, b1, b2, b3);
    }
    lAi += rsA; lBi += rsB;
#pragma unroll
    for (int mt = 0; mt < 4; ++mt) {
        int d = mt * 16 + l15;
#pragma unroll
        for (int nt = 0; nt < 4; ++nt) {
            int pc = (2 * nt + (quad >> 1)) ^ (d & 7);
            half4 vf = *(const half4*)(Vs + d * 64 + pc * 8 + (quad & 1) * 4);
            oA[mt] = __builtin_amdgcn_mfma_f32_16x16x16f16(vf, pAh[nt], oA[mt], 0, 0, 0);
            oB[mt] = __builtin_amdgcn_mfma_f32_16x16x16f16(vf, pBh[nt], oB[mt], 0, 0, 0);
        }
    }
}

__global__ __launch_bounds__(256)
void attn_fwd(const _Float16* __restrict__ q16, const _Float16* __restrict__ k16,
              const _Float16* __restrict__ v16, _Float16* __restrict__ o16)
{
    __shared__ __align__(16) _Float16 Ks[2][64 * 64];
    __shared__ __align__(16) _Float16 Vs[2][64 * 64];
    const int tid = threadIdx.x, lane = tid & 63, wave = tid >> 6;
    const int l15 = lane & 15, quad = lane >> 4;

    const int L   = blockIdx.x + 16 * blockIdx.y;
    const int qtA = (L >> 3) & 15;             // 0..15
    const int bh  = (L & 7) + ((L >> 7) << 3); // 0..63
    const int qtB = 31 - qtA;                  // 16..31
    const int b = bh >> 4, h = bh & 15;
    const int q0A = qtA * 64, q0B = qtB * 64;
    const _Float16* qp = q16 + (size_t)bh * TSEQ * HD;
    const _Float16* kp = k16 + (size_t)bh * TSEQ * HD;
    const _Float16* vp = v16 + (size_t)bh * HD * TSEQ;

    const int relq = wave * 16 + l15;
    half8 qA0 = *(const half8*)(qp + (size_t)(q0A + relq) * HD + quad * 8);
    half8 qA1 = *(const half8*)(qp + (size_t)(q0A + relq) * HD + 32 + quad * 8);
    half8 qB0 = *(const half8*)(qp + (size_t)(q0B + relq) * HD + quad * 8);
    half8 qB1 = *(const half8*)(qp + (size_t)(q0B + relq) * HD + 32 + quad * 8);

    float mA = -INFINITY, lA = 0.f, mB = -INFINITY, lB = 0.f;
    floatx4 oA[4], oB[4];
#pragma unroll
    for (int mt = 0; mt < 4; ++mt) { oA[mt] = (floatx4){0.f,0.f,0.f,0.f}; oB[mt] = (floatx4){0.f,0.f,0.f,0.f}; }

#define STAGE_KV(kt0, buf)                                                     \
    {                                                                          \
        _Float16* kd = Ks[buf];                                                \
        _Float16* vd = Vs[buf];                                                \
        _Pragma("unroll")                                                      \
        for (int p = 0; p < 2; ++p) {                                          \
            int ci = p * 256 + tid;                                            \
            int row = ci >> 3;                                                 \
            int c2 = (ci & 7) ^ (row & 7);                                     \
            lds_dma16(kp + (size_t)((kt0) + row) * HD + c2 * 8, kd + ci * 8);  \
            lds_dma16(vp + (size_t)row * TSEQ + (kt0) + c2 * 8, vd + ci * 8);  \
        }                                                                      \
    }

    STAGE_KV(0, 0);
    for (int kt = 0; kt <= qtA; ++kt) {
        const int cur = kt & 1;
        __syncthreads();
        STAGE_KV((kt + 1) * 64, cur ^ 1);
        attn_tile2(qA0, qA1, qB0, qB1, mA, lA, oA, mB, lB, oB,
                   Ks[cur], Vs[cur], (kt == qtA), l15, quad, relq);
    }
    for (int kt = qtA + 1; kt <= qtB; ++kt) {
        const int cur = kt & 1;
        __syncthreads();
        if (kt < qtB) STAGE_KV((kt + 1) * 64, cur ^ 1);
        attn_tile(qB0, qB1, mB, lB, oB, Ks[cur], Vs[cur], (kt == qtB), l15, quad, relq);
    }
#undef STAGE_KV

    lA += __shfl_xor(lA, 16, 64); lA += __shfl_xor(lA, 32, 64);
    lB += __shfl_xor(lB, 16, 64); lB += __shfl_xor(lB, 32, 64);
    const float invA = 1.f / lA, invB = 1.f / lB;
    const size_t baseA = ((size_t)(b * TSEQ + q0A + relq)) * CEMB + h * HD + quad * 4;
    const size_t baseB = ((size_t)(b * TSEQ + q0B + relq)) * CEMB + h * HD + quad * 4;
#pragma unroll
    for (int mt = 0; mt < 4; ++mt) {
        half4 ha = { (_Float16)(oA[mt][0] * invA), (_Float16)(oA[mt][1] * invA),
                     (_Float16)(oA[mt][2] * invA), (_Float16)(oA[mt][3] * invA) };
        half4 hb = { (_Float16)(oB[mt][0] * invB), (_Float16)(oB[mt][1] * invB),
                     (_Float16)(oB[mt][2] * invB), (_Float16)(oB[mt][3] * invB) };
        *(half4*)(o16 + baseA + mt * 16) = ha;
        *(half4*)(o16 + baseB + mt * 16) = hb;
    }
}

// ---------------------------------------------------------------------------
// Kernel 3: y = attn16 @ Wp16^T + b_proj, fp32 out. 128x128 tile, 512
// blocks. GRID MUST BE (8, 64) — swizzle assumes L in [0,512).
// ---------------------------------------------------------------------------
__global__ __launch_bounds__(256)
void proj_gemm(const _Float16* __restrict__ A, const _Float16* __restrict__ B,
               const float* __restrict__ bias, float* __restrict__ out)
{
    __shared__ __align__(16) _Float16 smem[16384];   // 32 KB dbuf tiles
    const int tid = threadIdx.x, lane = tid & 63, wave = tid >> 6;
    const int wm = wave & 1, wn = wave >> 1;
    const int L  = blockIdx.x + 8 * blockIdx.y;      // 0..511
    const int jj = L >> 3;                            // 0..63
    const int m0 = ((L & 7) + 8 * (jj & 7)) * 128;   // XCD's 8 panels
    const int n0 = (jj >> 3) * 128;                  // 0..7 panels
    const int l15 = lane & 15, quad = lane >> 4;

    floatx4 acc[4][4];
#pragma unroll
    for (int i = 0; i < 4; ++i)
#pragma unroll
        for (int j = 0; j < 4; ++j) acc[i][j] = (floatx4){0.f, 0.f, 0.f, 0.f};

    stage32(A, smem, m0, 0, tid);
    stage32(B, smem + 8192, n0, 0, tid);
    for (int kt = 0; kt < 32; ++kt) {
        const int cur = kt & 1;
        _Float16* Asc = smem + cur * 4096;
        _Float16* Bsc = smem + 8192 + cur * 4096;
        __syncthreads();
        if (kt < 31) {
            stage32(A, smem + (cur ^ 1) * 4096, m0, (kt + 1) * 32, tid);
            stage32(B, smem + 8192 + (cur ^ 1) * 4096, n0, (kt + 1) * 32, tid);
        }
        half8 af[4], bf[4];
#pragma unroll
        for (int mt = 0; mt < 4; ++mt) {
            int row = wm * 64 + mt * 16 + l15;
            af[mt] = *(const half8*)(Asc + row * 32 + (quad ^ (row & 3)) * 8);
        }
#pragma unroll
        for (int nt = 0; nt < 4; ++nt) {
            int row = wn * 64 + nt * 16 + l15;
            bf[nt] = *(const half8*)(Bsc + row * 32 + (quad ^ (row & 3)) * 8);
        }
#pragma unroll
        for (int mt = 0; mt < 4; ++mt)
#pragma unroll
            for (int nt = 0; nt < 4; ++nt)
                acc[mt][nt] = __builtin_amdgcn_mfma_f32_16x16x32_f16(af[mt], bf[nt], acc[mt][nt], 0, 0, 0);
    }

    const int rbase = quad << 2;
#pragma unroll
    for (int mt = 0; mt < 4; ++mt)
#pragma unroll
        for (int nt = 0; nt < 4; ++nt) {
            int gn = n0 + wn * 64 + nt * 16 + l15;
            float bb = bias[gn];
#pragma unroll
            for (int r = 0; r < 4; ++r) {
                int gm = m0 + wm * 64 + mt * 16 + rbase + r;
                out[(size_t)gm * CEMB + gn] = acc[mt][nt][r] + bb;
            }
        }
}

// ---------------------------------------------------------------------------
extern "C" void kernel_launch(void* const* d_in, const int* in_sizes, int n_in,
                              void* d_out, int out_size, void* d_ws, size_t ws_size,
                              hipStream_t stream) {
    const float* x     = (const float*)d_in[0];
    const float* Wattn = (const float*)d_in[1];
    const float* Wproj = (const float*)d_in[2];
    const float* bproj = (const float*)d_in[3];
    float* out = (float*)d_out;

    const size_t nx  = (size_t)BATCH * TSEQ * CEMB;
    const size_t nwa = (size_t)3 * CEMB * CEMB;
    const size_t nwp = (size_t)CEMB * CEMB;
    const size_t per = (size_t)BATCH * NHEAD * TSEQ * HD;

    _Float16* x16    = (_Float16*)d_ws;
    _Float16* wa16   = x16 + nx;
    _Float16* wp16   = wa16 + nwa;
    _Float16* q16    = wp16 + nwp;
    _Float16* k16    = q16 + per;
    _Float16* v16    = k16 + per;
    _Float16* attn16 = x16;   // alias: x16 fully consumed before attn writes

    const int nconv = (int)((nx + nwa + nwp) / 4);
    cvt_fp16<<<nconv / 256, 256, 0, stream>>>(x, Wattn, Wproj, x16, wa16, wp16);
    qk_gemm<<<dim3(8, 32), 512, 0, stream>>>(x16, wa16, q16, k16);
    v_gemm<<<dim3(8, 64), 256, 0, stream>>>(x16, wa16, v16);
    attn_fwd<<<dim3(16, BATCH * NHEAD), 256, 0, stream>>>(q16, k16, v16, attn16);
    proj_gemm<<<dim3(CEMB / 128, MROWS / 128), 256, 0, stream>>>(attn16, wp16, bproj, out);
}